// Round 5
// baseline (103.003 us; speedup 1.0000x reference)
//
#include <hip/hip_runtime.h>

// Problem constants
#define HWSZ 65536             // 256*256
#define PLANE (3 * HWSZ)       // one batch's [3,H,W]
#define OUTSTRIDE (8 * PLANE)  // one full output tensor [8,3,256,256]
#define MAGIC 0x13572468       // != 0xAAAAAAAA ws poison

// ws layout (floats):
//   pA      = ws + 0       [4][8][2][192]  layer-2 split-K partials (no pb2)
//   partial = ws + 12288   [4][8][192]     fc2 split-K partials (fb2 in c4==0)
//   fbase   = (int*)(ws + 20480): flag i at fbase[i*32] (128B stride).
//     i = 0..63  : phase-A done, i = b*8 + s (s = k*2+half)
//     i = 64..95 : phase-B done, i = 64 + c4*8 + b
//
// One kernel, 256 blocks x 512 threads (1 block/CU -> all co-resident, no
// dispatch-order deadlock; flag producers are blocks 0..63). Blocks 0..63 run
// the R4 MLP (phase A for (b,s); phase B for s<4) then render their tile;
// blocks 64..255 prefetch x into VGPRs and spin (LOAD-ONLY agent-scope spins
// -- R1's atomicAdd-RMW spin serialized the coherence point and regressed).
// Gray outputs (12.6MB of the 18.9MB stores) need only the 4 phase-A flags of
// k=0,1; only o0 waits for the 4 phase-B flags.
__device__ __forceinline__ void waitflag(const int* p) {
  while (__hip_atomic_load(p, __ATOMIC_RELAXED, __HIP_MEMORY_SCOPE_AGENT) !=
         MAGIC)
    __builtin_amdgcn_s_sleep(4);
}

__global__ __launch_bounds__(512) void k_fused(
    const float* __restrict__ x,
    const float* __restrict__ f, const float* __restrict__ bf,
    const float* __restrict__ pw1, const float* __restrict__ pb1,
    const float* __restrict__ pw2, const float* __restrict__ pb2,
    const float* __restrict__ fw1, const float* __restrict__ fb1,
    const float* __restrict__ fw2, const float* __restrict__ fb2,
    float* __restrict__ ws, float* __restrict__ out) {
  __shared__ float smem[2304];
  __shared__ float2 tab[576];
  const int t = threadIdx.x, bid = blockIdx.x;

  float* pA      = ws;          // [4,8,2,192]
  float* partial = ws + 12288;  // [4,8,192]
  int* fbase = (int*)(ws + 20480);

  // render tile for this block
  const int bx = bid >> 3, b_r = bid & 7;
  const int s4 = bx * 512 + t;
  const float* xb = x + (size_t)b_r * PLANE;
  float4 vr, vg, vb;

  const bool is_mlp = (bid < 64);
  if (!is_mlp) {
    // prefetch x into registers before parking in any spin
    vr = ((const float4*)(xb))[s4];
    vg = ((const float4*)(xb + HWSZ))[s4];
    vb = ((const float4*)(xb + 2 * HWSZ))[s4];
    asm volatile("" :: "v"(vr.x), "v"(vg.x), "v"(vb.x));
  }

  if (is_mlp) {
    const int s = bid & 7, b = bid >> 3;       // slice, mlp-batch
    const int k = s >> 1, half = s & 1, o0c = half * 96;

    // ======== Phase A: layer1 output-half + layer2 split-K ========
    {
      float* sf  = smem;           // 512
      float* red = smem + 512;     // 16*96 (then 8*192)
      float* sh  = smem + 2048;    // 96 (own h half)

      const float* feat = ((k & 1) ? bf : f) + b * 512;
      sf[t] = feat[t & 511];  // t in 0..511 covers exactly 512
      __syncthreads();

      if (t < 384) {  // layer1: 512 -> 96 (cols o0c..o0c+95)
        int q = t % 24, sr = t / 24;  // sr in 0..15, 32 rows each
        const float4* w = (const float4*)(pw1 + (size_t)k * (512 * 192));
        int icol = half * 24 + q;
        float4 acc = {0.f, 0.f, 0.f, 0.f};
        int i0 = sr * 32;
        for (int r = 0; r < 2; ++r) {
          float4 wv[16];
#pragma unroll
          for (int j = 0; j < 16; ++j)
            wv[j] = w[(size_t)(i0 + r * 16 + j) * 48 + icol];
#pragma unroll
          for (int j = 0; j < 16; ++j) {
            float v = sf[i0 + r * 16 + j];
            acc.x = fmaf(v, wv[j].x, acc.x); acc.y = fmaf(v, wv[j].y, acc.y);
            acc.z = fmaf(v, wv[j].z, acc.z); acc.w = fmaf(v, wv[j].w, acc.w);
          }
        }
        ((float4*)(red + sr * 96))[q] = acc;
      }
      __syncthreads();
      if (t < 96) {
        float a = pb1[k * 192 + o0c + t];
#pragma unroll
        for (int s2 = 0; s2 < 16; ++s2) a += red[s2 * 96 + t];
        sh[t] = fmaxf(a, 0.f);
      }
      __syncthreads();
      if (t < 384) {  // layer2 split-K: own 96 h-rows x all 192 cols
        int q2 = t % 48, s2 = t / 48;  // s2 in 0..7
        const float4* w = (const float4*)(pw2 + (size_t)k * (192 * 192));
        float4 acc = {0.f, 0.f, 0.f, 0.f};
        float4 wv[12];
#pragma unroll
        for (int j = 0; j < 12; ++j)
          wv[j] = w[(size_t)(o0c + s2 * 12 + j) * 48 + q2];
#pragma unroll
        for (int j = 0; j < 12; ++j) {
          float v = sh[s2 * 12 + j];
          acc.x = fmaf(v, wv[j].x, acc.x); acc.y = fmaf(v, wv[j].y, acc.y);
          acc.z = fmaf(v, wv[j].z, acc.z); acc.w = fmaf(v, wv[j].w, acc.w);
        }
        ((float4*)(red + s2 * 192))[q2] = acc;
      }
      __syncthreads();
      if (t < 192) {
        float a = 0.f;  // pb2 added by consumers
#pragma unroll
        for (int s3 = 0; s3 < 8; ++s3) a += red[s3 * 192 + t];
        pA[((k * 8 + b) * 2 + half) * 192 + t] = a;
      }
      __syncthreads();  // drain stores before fence
      if (t == 0) {
        __threadfence();
        atomicExch(&fbase[bid * 32], MAGIC);
      }
    }

    if (s < 4) {
      // ======== Phase B: fc1 quarter + local split-K fc2 ========
      const int b2 = b, c4 = s, ob2 = c4 * 48;
      int q = t % 12, sb = t / 12;   // fc1 layout (t<384: sb 0..31)
      int q2 = t % 48, s2 = t / 48;  // fc2 layout (t<384: s2 0..7)

      float4 wv1[18];
      if (t < 384) {  // prefetch fw1 slice BEFORE the spin
        const float4* w = (const float4*)fw1;
        int i0 = sb * 18;
#pragma unroll
        for (int j = 0; j < 18; ++j)
          wv1[j] = w[(size_t)(i0 + j) * 48 + c4 * 12 + q];
      }
      float4 wv2[6];
      if (t < 384) {  // prefetch fw2 rows BEFORE the spin
        const float4* w = (const float4*)fw2;
#pragma unroll
        for (int j = 0; j < 6; ++j)
          wv2[j] = w[(size_t)(ob2 + s2 * 6 + j) * 48 + q2];
      }

      if (t < 8) waitflag(&fbase[((b2 << 3) + t) * 32]);
      __syncthreads();
      if (t == 0) __threadfence();  // acquire
      __syncthreads();

      {
        float* sc  = smem;           // 576 (cat input)
        float* red = smem + 576;     // 32*48 (fc1 reduce)
        for (int idx = t; idx < 576; idx += 512) {
          float v;
          if (idx < 192) {
            const float* p0 = pA + ((0 * 8 + b2) * 2) * 192;
            v = p0[idx] + p0[192 + idx] + pb2[idx];
          } else if (idx < 384) {
            int jj = idx - 192;
            const float* p1 = pA + ((1 * 8 + b2) * 2) * 192;
            v = p1[jj] + p1[192 + jj] + pb2[192 + jj];
          } else {
            int jj = idx - 384;
            const float* p2 = pA + ((2 * 8 + b2) * 2) * 192;
            const float* p3 = pA + ((3 * 8 + b2) * 2) * 192;
            v = p2[jj] + p2[192 + jj] + p3[jj] + p3[192 + jj] +
                pb2[384 + jj] + pb2[576 + jj];
          }
          sc[idx] = v;
        }
        __syncthreads();
        if (t < 384) {  // fc1: 576 -> 48
          float4 acc = {0.f, 0.f, 0.f, 0.f};
          int i0 = sb * 18;
#pragma unroll
          for (int j = 0; j < 18; ++j) {
            float v = sc[i0 + j];
            acc.x = fmaf(v, wv1[j].x, acc.x); acc.y = fmaf(v, wv1[j].y, acc.y);
            acc.z = fmaf(v, wv1[j].z, acc.z); acc.w = fmaf(v, wv1[j].w, acc.w);
          }
          ((float4*)(red + sb * 48))[q] = acc;
        }
        __syncthreads();
        if (t < 48) {  // h quarter -> smem[0..47]
          float a = fb1[ob2 + t];
#pragma unroll
          for (int s3 = 0; s3 < 32; ++s3) a += red[s3 * 48 + t];
          smem[t] = fmaxf(a, 0.f);
        }
        __syncthreads();
        if (t < 384) {  // fc2 split-K
          float4 acc = {0.f, 0.f, 0.f, 0.f};
#pragma unroll
          for (int j = 0; j < 6; ++j) {
            float v = smem[s2 * 6 + j];
            acc.x = fmaf(v, wv2[j].x, acc.x); acc.y = fmaf(v, wv2[j].y, acc.y);
            acc.z = fmaf(v, wv2[j].z, acc.z); acc.w = fmaf(v, wv2[j].w, acc.w);
          }
          ((float4*)(red + s2 * 192))[q2] = acc;
        }
        __syncthreads();
        if (t < 192) {
          float a = (c4 == 0) ? fb2[t] : 0.f;  // bias added exactly once
#pragma unroll
          for (int s3 = 0; s3 < 8; ++s3) a += red[s3 * 192 + t];
          partial[(c4 * 8 + b2) * 192 + t] = a;
        }
        __syncthreads();  // drain stores before fence
        if (t == 0) {
          __threadfence();
          atomicExch(&fbase[(64 + c4 * 8 + b2) * 32], MAGIC);
        }
      }
    }

    // MLP done; now fetch this block's render tile (late is fine)
    vr = ((const float4*)(xb))[s4];
    vg = ((const float4*)(xb + HWSZ))[s4];
    vb = ((const float4*)(xb + 2 * HWSZ))[s4];
  }

  // ======== Stage G: gray outputs o1,o2 — need phase-A slices 0..3 ========
  if (t < 4) waitflag(&fbase[(b_r * 8 + t) * 32]);
  __syncthreads();
  if (t == 0) __threadfence();  // acquire
  __syncthreads();

  const int wave = t >> 6, lane = t & 63;
  if (wave < 6) {  // build LUTs for curves 3..8 (gray, param_f / param_b)
    int cur = 3 + wave;
    int oi = cur / 3, c = cur - oi * 3;  // oi = 1,2
    const float* pa = pA + (((oi - 1) * 8 + b_r) * 2) * 192 + c * 64;
    float p = pa[lane] + pa[192 + lane] +
              pb2[(oi - 1) * 192 + c * 64 + lane];
    float v = p;  // inclusive scan
#pragma unroll
    for (int d = 1; d < 64; d <<= 1) {
      float n = __shfl_up(v, d, 64);
      if (lane >= d) v += n;
    }
    float total = __shfl(v, 63, 64);
    float norm = 64.f / (total + 1e-30f);
    tab[cur * 64 + lane] = make_float2((v - p) * 0.015625f * norm, p * norm);
  }
  __syncthreads();

  auto idx_of = [&](float v, int& kk, float& tt) {
    int k2 = (int)(v * 64.f);
    k2 = k2 < 0 ? 0 : (k2 > 63 ? 63 : k2);
    kk = k2;
    tt = v - (float)k2 * 0.015625f;
  };
  auto evk = [&](int cur, int k2, float tt) -> float {
    float2 e = tab[cur * 64 + k2];
    return fmaf(tt, e.y, e.x);
  };

  float* o0 = out + (size_t)b_r * PLANE;
  float* o1 = out + OUTSTRIDE + (size_t)b_r * PLANE;
  float* o2 = out + 2 * OUTSTRIDE + (size_t)b_r * PLANE;

  {
    float4 gr;
    gr.x = fmaf(0.299f, vr.x, fmaf(0.587f, vg.x, 0.114f * vb.x));
    gr.y = fmaf(0.299f, vr.y, fmaf(0.587f, vg.y, 0.114f * vb.y));
    gr.z = fmaf(0.299f, vr.z, fmaf(0.587f, vg.z, 0.114f * vb.z));
    gr.w = fmaf(0.299f, vr.w, fmaf(0.587f, vg.w, 0.114f * vb.w));

    int kx, ky, kz, kw; float tx, ty, tz, tw;
    idx_of(gr.x, kx, tx); idx_of(gr.y, ky, ty);
    idx_of(gr.z, kz, tz); idx_of(gr.w, kw, tw);
#pragma unroll
    for (int c = 0; c < 3; ++c) {
      float4 r;
      r.x = evk(3 + c, kx, tx); r.y = evk(3 + c, ky, ty);
      r.z = evk(3 + c, kz, tz); r.w = evk(3 + c, kw, tw);
      ((float4*)(o1 + c * HWSZ))[s4] = r;
    }
#pragma unroll
    for (int c = 0; c < 3; ++c) {
      float4 r;
      r.x = evk(6 + c, kx, tx); r.y = evk(6 + c, ky, ty);
      r.z = evk(6 + c, kz, tz); r.w = evk(6 + c, kw, tw);
      ((float4*)(o2 + c * HWSZ))[s4] = r;
    }
  }

  // ======== Stage F: o0 — needs the 4 phase-B (fc2) flags ========
  if (t < 4) waitflag(&fbase[(64 + t * 8 + b_r) * 32]);
  __syncthreads();
  if (t == 0) __threadfence();  // acquire
  __syncthreads();

  if (wave < 3) {  // build LUTs for curves 0..2 (full param, 4 partials)
    const float* pp = partial + b_r * 192 + wave * 64;
    float p = pp[lane] + pp[1536 + lane] + pp[3072 + lane] + pp[4608 + lane];
    float v = p;
#pragma unroll
    for (int d = 1; d < 64; d <<= 1) {
      float n = __shfl_up(v, d, 64);
      if (lane >= d) v += n;
    }
    float total = __shfl(v, 63, 64);
    float norm = 64.f / (total + 1e-30f);
    tab[wave * 64 + lane] = make_float2((v - p) * 0.015625f * norm, p * norm);
  }
  __syncthreads();

  {
    auto ev4 = [&](int cur, float4 v4) -> float4 {
      int k2; float tt; float4 r;
      idx_of(v4.x, k2, tt); r.x = evk(cur, k2, tt);
      idx_of(v4.y, k2, tt); r.y = evk(cur, k2, tt);
      idx_of(v4.z, k2, tt); r.z = evk(cur, k2, tt);
      idx_of(v4.w, k2, tt); r.w = evk(cur, k2, tt);
      return r;
    };
    ((float4*)(o0))[s4]            = ev4(0, vr);
    ((float4*)(o0 + HWSZ))[s4]     = ev4(1, vg);
    ((float4*)(o0 + 2 * HWSZ))[s4] = ev4(2, vb);
  }
}

// ---------------------------------------------------------------------------
extern "C" void kernel_launch(void* const* d_in, const int* in_sizes, int n_in,
                              void* d_out, int out_size, void* d_ws, size_t ws_size,
                              hipStream_t stream) {
  const float* x   = (const float*)d_in[0];
  const float* f   = (const float*)d_in[1];
  const float* bf  = (const float*)d_in[2];
  const float* pw1 = (const float*)d_in[3];
  const float* pb1 = (const float*)d_in[4];
  const float* pw2 = (const float*)d_in[5];
  const float* pb2 = (const float*)d_in[6];
  const float* fw1 = (const float*)d_in[7];
  const float* fb1 = (const float*)d_in[8];
  const float* fw2 = (const float*)d_in[9];
  const float* fb2 = (const float*)d_in[10];
  float* out = (float*)d_out;
  float* ws  = (float*)d_ws;

  k_fused<<<256, 512, 0, stream>>>(x, f, bf, pw1, pb1, pw2, pb2,
                                   fw1, fb1, fw2, fb2, ws, out);
}

// Round 6
// 93.658 us; speedup vs baseline: 1.0998x; 1.0998x over previous
//
#include <hip/hip_runtime.h>

// Problem constants
#define HWSZ 65536             // 256*256
#define PLANE (3 * HWSZ)       // one batch's [3,H,W]
#define OUTSTRIDE (8 * PLANE)  // one full output tensor [8,3,256,256]
#define MAGIC 0x13572468       // != 0xAAAAAAAA ws poison

// ws layout (floats):
//   pA      = ws + 0       [4][8][2][192]  layer-2 split-K partials (no pb2)
//   partial = ws + 12288   [4][8][192]     fc2 split-K partials (fb2 in c4==0)
//   fbase   = (int*)(ws + 20480), flag i at fbase[i*16], i = b*8 + slice
//
// 64 phase-A blocks: blk = b*8 + s, s = k*2 + half. XCD(blk)=blk%8=s, so all
// 8 batch-sharers of one weight slice sit on ONE XCD -> slice is HBM-fetched
// once per XCD, re-served from L2. Per-block weight bytes halved vs 32-block
// layout (196KB pw1-half + 73KB pw2-rows), still exactly ONE global sync.
//
// NOTE (R1/R5 evidence): fusing MLP+render into one kernel regressed twice
// (+8.6 us with RMW spins, +7.8 us with load-only spins). The kernel boundary
// is the cheapest global barrier here — keep the 2-kernel pipeline.
__global__ __launch_bounds__(384) void k_mlp(
    const float* __restrict__ f, const float* __restrict__ bf,
    const float* __restrict__ pw1, const float* __restrict__ pb1,
    const float* __restrict__ pw2, const float* __restrict__ pb2,
    const float* __restrict__ fw1, const float* __restrict__ fb1,
    const float* __restrict__ fw2, const float* __restrict__ fb2,
    float* __restrict__ ws) {
  __shared__ float smem[2304];
  int t = threadIdx.x, blk = blockIdx.x;

  float* pA      = ws;          // [4,8,2,192]
  float* partial = ws + 12288;  // [4,8,192]
  int* fbase = (int*)(ws + 20480);

  // ======== Phase A: layer1 output-half + layer2 split-K for (k,b,half) ===
  int s = blk & 7, b = blk >> 3;
  int k = s >> 1, half = s & 1, o0 = half * 96;
  {
    float* sf  = smem;           // 512
    float* red = smem + 512;     // 16*96 (then 8*192)
    float* sh  = smem + 2048;    // 96 (own h half)

    const float* feat = ((k & 1) ? bf : f) + b * 512;
    for (int i = t; i < 512; i += 384) sf[i] = feat[i];
    __syncthreads();

    {  // layer1: 512 -> 96 (cols o0..o0+95)
      int q = t % 24, sr = t / 24;  // sr in 0..15, 32 rows each
      const float4* w = (const float4*)(pw1 + (size_t)k * (512 * 192));
      int icol = half * 24 + q;
      float4 acc = {0.f, 0.f, 0.f, 0.f};
      int i0 = sr * 32;
      for (int r = 0; r < 2; ++r) {
        float4 wv[16];
#pragma unroll
        for (int j = 0; j < 16; ++j)
          wv[j] = w[(size_t)(i0 + r * 16 + j) * 48 + icol];
#pragma unroll
        for (int j = 0; j < 16; ++j) {
          float v = sf[i0 + r * 16 + j];
          acc.x = fmaf(v, wv[j].x, acc.x); acc.y = fmaf(v, wv[j].y, acc.y);
          acc.z = fmaf(v, wv[j].z, acc.z); acc.w = fmaf(v, wv[j].w, acc.w);
        }
      }
      ((float4*)(red + sr * 96))[q] = acc;
    }
    __syncthreads();
    if (t < 96) {
      float a = pb1[k * 192 + o0 + t];
#pragma unroll
      for (int s2 = 0; s2 < 16; ++s2) a += red[s2 * 96 + t];
      sh[t] = fmaxf(a, 0.f);
    }
    __syncthreads();
    {  // layer2 split-K: own 96 h-rows x all 192 cols -> pA partial
      int q2 = t % 48, s2 = t / 48;  // s2 in 0..7, 12 rows each
      const float4* w = (const float4*)(pw2 + (size_t)k * (192 * 192));
      float4 acc = {0.f, 0.f, 0.f, 0.f};
      float4 wv[12];
#pragma unroll
      for (int j = 0; j < 12; ++j)
        wv[j] = w[(size_t)(o0 + s2 * 12 + j) * 48 + q2];
#pragma unroll
      for (int j = 0; j < 12; ++j) {
        float v = sh[s2 * 12 + j];
        acc.x = fmaf(v, wv[j].x, acc.x); acc.y = fmaf(v, wv[j].y, acc.y);
        acc.z = fmaf(v, wv[j].z, acc.z); acc.w = fmaf(v, wv[j].w, acc.w);
      }
      ((float4*)(red + s2 * 192))[q2] = acc;
    }
    __syncthreads();
    if (t < 192) {
      float a = 0.f;  // pb2 added by consumers (once per (k,b) sum)
#pragma unroll
      for (int s3 = 0; s3 < 8; ++s3) a += red[s3 * 192 + t];
      pA[((k * 8 + b) * 2 + half) * 192 + t] = a;
    }
    __syncthreads();  // drain stores before fence
    if (t == 0) {
      __threadfence();
      atomicExch(&fbase[blk * 16], MAGIC);
    }
  }

  if (s >= 4) return;  // blocks 4..7 per b: phase A only

  // ======== Phase B: fc1 quarter + local split-K fc2 (blocks s<4) ========
  int b2 = b, c4 = s, ob2 = c4 * 48;
  int q = t % 12, sb = t / 12;   // sb in 0..31 (fc1 layout)
  int q2 = t % 48, s2 = t / 48;  // s2 in 0..7 (fc2 split-K layout)

  // prefetch fw1 slice AND fw2 rows (independent of pA) BEFORE the spin
  float4 wv1[18];
  {
    const float4* w = (const float4*)fw1;
    int i0 = sb * 18;
#pragma unroll
    for (int j = 0; j < 18; ++j)
      wv1[j] = w[(size_t)(i0 + j) * 48 + c4 * 12 + q];
  }
  float4 wv2[6];
  {
    const float4* w = (const float4*)fw2;
#pragma unroll
    for (int j = 0; j < 6; ++j)
      wv2[j] = w[(size_t)(ob2 + s2 * 6 + j) * 48 + q2];
  }

  if (t < 8) {  // need all 8 slices of this b
    while (atomicAdd(&fbase[((b2 << 3) + t) * 16], 0) != MAGIC)
      __builtin_amdgcn_s_sleep(2);
  }
  __syncthreads();
  if (t == 0) __threadfence();  // acquire
  __syncthreads();

  {
    float* sc  = smem;           // 576 (cat input)
    float* red = smem + 576;     // 32*48 (fc1 reduce)
    for (int idx = t; idx < 576; idx += 384) {
      float v;
      if (idx < 192) {
        const float* p0 = pA + ((0 * 8 + b2) * 2) * 192;
        v = p0[idx] + p0[192 + idx] + pb2[idx];
      } else if (idx < 384) {
        int jj = idx - 192;
        const float* p1 = pA + ((1 * 8 + b2) * 2) * 192;
        v = p1[jj] + p1[192 + jj] + pb2[192 + jj];
      } else {
        int jj = idx - 384;
        const float* p2 = pA + ((2 * 8 + b2) * 2) * 192;
        const float* p3 = pA + ((3 * 8 + b2) * 2) * 192;
        v = p2[jj] + p2[192 + jj] + p3[jj] + p3[192 + jj] +
            pb2[384 + jj] + pb2[576 + jj];
      }
      sc[idx] = v;
    }
    __syncthreads();
    {  // fc1: 576 -> 48 (this block's output quarter)
      float4 acc = {0.f, 0.f, 0.f, 0.f};
      int i0 = sb * 18;
#pragma unroll
      for (int j = 0; j < 18; ++j) {
        float v = sc[i0 + j];
        acc.x = fmaf(v, wv1[j].x, acc.x); acc.y = fmaf(v, wv1[j].y, acc.y);
        acc.z = fmaf(v, wv1[j].z, acc.z); acc.w = fmaf(v, wv1[j].w, acc.w);
      }
      ((float4*)(red + sb * 48))[q] = acc;
    }
    __syncthreads();
    if (t < 48) {  // h quarter -> smem[0..47] (sc area dead now)
      float a = fb1[ob2 + t];
#pragma unroll
      for (int s3 = 0; s3 < 32; ++s3) a += red[s3 * 48 + t];
      smem[t] = fmaxf(a, 0.f);
    }
    __syncthreads();
    {  // fc2 split-K: partial[j] = sum_{i in quarter} h[i]*fw2[i][j]
      float4 acc = {0.f, 0.f, 0.f, 0.f};
#pragma unroll
      for (int j = 0; j < 6; ++j) {
        float v = smem[s2 * 6 + j];
        acc.x = fmaf(v, wv2[j].x, acc.x); acc.y = fmaf(v, wv2[j].y, acc.y);
        acc.z = fmaf(v, wv2[j].z, acc.z); acc.w = fmaf(v, wv2[j].w, acc.w);
      }
      ((float4*)(red + s2 * 192))[q2] = acc;
    }
    __syncthreads();
    if (t < 192) {
      float a = (c4 == 0) ? fb2[t] : 0.f;  // bias added exactly once
#pragma unroll
      for (int s3 = 0; s3 < 8; ++s3) a += red[s3 * 192 + t];
      partial[(c4 * 8 + b2) * 192 + t] = a;
    }
    // no fence/flag: kernel-boundary release + stream order covers k_render
  }
}

// ---------------------------------------------------------------------------
// Render: 256 blocks (32,8) x 256 threads, 2 float4 per thread per channel.
// LUT entry e[k] = {S_k*norm/64, p_k*norm}. Gray curves share k/tt.
// Curves 0..2 sum the 4 fc2 partials; curves 3..8 sum the 2 pA halves + pb2.
__global__ __launch_bounds__(256) void k_render(
    const float* __restrict__ x, const float* __restrict__ ws,
    const float* __restrict__ pb2, float* __restrict__ out) {
  int b = blockIdx.y, t = threadIdx.x;
  int wave = t >> 6, lane = t & 63;
  const float* pA      = ws;
  const float* partial = ws + 12288;
  __shared__ float2 tab[576];

  // prefetch both x float4 groups
  int s4a = blockIdx.x * 512 + t, s4b = s4a + 256;
  const float* xb = x + (size_t)b * PLANE;
  float4 vr0 = ((const float4*)(xb))[s4a];
  float4 vr1 = ((const float4*)(xb))[s4b];
  float4 vg0 = ((const float4*)(xb + HWSZ))[s4a];
  float4 vg1 = ((const float4*)(xb + HWSZ))[s4b];
  float4 vb0 = ((const float4*)(xb + 2 * HWSZ))[s4a];
  float4 vb1 = ((const float4*)(xb + 2 * HWSZ))[s4b];

  for (int cur = wave; cur < 9; cur += 4) {
    int oi = cur / 3, c = cur - oi * 3;
    float p;
    if (oi == 0) {
      const float* pp = partial + b * 192 + c * 64;
      p = pp[lane] + pp[1536 + lane] + pp[3072 + lane] + pp[4608 + lane];
    } else {
      const float* pa = pA + (((oi - 1) * 8 + b) * 2) * 192 + c * 64;
      p = pa[lane] + pa[192 + lane] + pb2[(oi - 1) * 192 + c * 64 + lane];
    }
    float v = p;  // inclusive scan
#pragma unroll
    for (int d = 1; d < 64; d <<= 1) {
      float n = __shfl_up(v, d, 64);
      if (lane >= d) v += n;
    }
    float total = __shfl(v, 63, 64);
    float norm = 64.f / (total + 1e-30f);
    tab[cur * 64 + lane] = make_float2((v - p) * 0.015625f * norm, p * norm);
  }
  __syncthreads();

  auto idx_of = [&](float v, int& kk, float& tt) {
    int k = (int)(v * 64.f);
    k = k < 0 ? 0 : (k > 63 ? 63 : k);
    kk = k;
    tt = v - (float)k * 0.015625f;
  };
  auto evk = [&](int cur, int k, float tt) -> float {
    float2 e = tab[cur * 64 + k];
    return fmaf(tt, e.y, e.x);
  };
  auto ev4 = [&](int cur, float4 v) -> float4 {
    int k; float tt; float4 r;
    idx_of(v.x, k, tt); r.x = evk(cur, k, tt);
    idx_of(v.y, k, tt); r.y = evk(cur, k, tt);
    idx_of(v.z, k, tt); r.z = evk(cur, k, tt);
    idx_of(v.w, k, tt); r.w = evk(cur, k, tt);
    return r;
  };

  float* o0 = out + (size_t)b * PLANE;
  float* o1 = out + OUTSTRIDE + (size_t)b * PLANE;
  float* o2 = out + 2 * OUTSTRIDE + (size_t)b * PLANE;

  auto process = [&](int s4, float4 vr, float4 vg, float4 vb) {
    float4 gr;
    gr.x = fmaf(0.299f, vr.x, fmaf(0.587f, vg.x, 0.114f * vb.x));
    gr.y = fmaf(0.299f, vr.y, fmaf(0.587f, vg.y, 0.114f * vb.y));
    gr.z = fmaf(0.299f, vr.z, fmaf(0.587f, vg.z, 0.114f * vb.z));
    gr.w = fmaf(0.299f, vr.w, fmaf(0.587f, vg.w, 0.114f * vb.w));

    ((float4*)(o0))[s4]            = ev4(0, vr);
    ((float4*)(o0 + HWSZ))[s4]     = ev4(1, vg);
    ((float4*)(o0 + 2 * HWSZ))[s4] = ev4(2, vb);

    // gray: shared piece index across curves 3..8
    int kx, ky, kz, kw; float tx, ty, tz, tw;
    idx_of(gr.x, kx, tx); idx_of(gr.y, ky, ty);
    idx_of(gr.z, kz, tz); idx_of(gr.w, kw, tw);
#pragma unroll
    for (int c = 0; c < 3; ++c) {
      float4 r;
      r.x = evk(3 + c, kx, tx); r.y = evk(3 + c, ky, ty);
      r.z = evk(3 + c, kz, tz); r.w = evk(3 + c, kw, tw);
      ((float4*)(o1 + c * HWSZ))[s4] = r;
    }
#pragma unroll
    for (int c = 0; c < 3; ++c) {
      float4 r;
      r.x = evk(6 + c, kx, tx); r.y = evk(6 + c, ky, ty);
      r.z = evk(6 + c, kz, tz); r.w = evk(6 + c, kw, tw);
      ((float4*)(o2 + c * HWSZ))[s4] = r;
    }
  };

  process(s4a, vr0, vg0, vb0);
  process(s4b, vr1, vg1, vb1);
}

// ---------------------------------------------------------------------------
extern "C" void kernel_launch(void* const* d_in, const int* in_sizes, int n_in,
                              void* d_out, int out_size, void* d_ws, size_t ws_size,
                              hipStream_t stream) {
  const float* x   = (const float*)d_in[0];
  const float* f   = (const float*)d_in[1];
  const float* bf  = (const float*)d_in[2];
  const float* pw1 = (const float*)d_in[3];
  const float* pb1 = (const float*)d_in[4];
  const float* pw2 = (const float*)d_in[5];
  const float* pb2 = (const float*)d_in[6];
  const float* fw1 = (const float*)d_in[7];
  const float* fb1 = (const float*)d_in[8];
  const float* fw2 = (const float*)d_in[9];
  const float* fb2 = (const float*)d_in[10];
  float* out = (float*)d_out;
  float* ws  = (float*)d_ws;

  k_mlp<<<64, 384, 0, stream>>>(f, bf, pw1, pb1, pw2, pb2, fw1, fb1, fw2,
                                fb2, ws);
  dim3 grid(32, 8);
  k_render<<<grid, 256, 0, stream>>>(x, ws, pb2, out);
}